// Round 15
// baseline (194.904 us; speedup 1.0000x reference)
//
#include <hip/hip_runtime.h>
#include <math.h>

#pragma clang fp contract(off)

#define NXP   8192
#define GROUP 4      // 4 lanes per x-point = numpy's 4 complex pairwise accumulators
#define CPN   32     // 32 sequential terms per accumulator (stride 4)
#define NITER 40
#define GS    8      // software-pipeline stage width

// Quad-lane butterfly add via DPP quad_perm (VALU pipe, no LDS).
template <int CTRL>
__device__ __forceinline__ float qxor_add(float v) {
    int s = __builtin_amdgcn_update_dpp(0, __float_as_int(v), CTRL, 0xF, 0xF, true);
    return v + __int_as_float(s);
}
#define RED4(v) do {                         \
    v = qxor_add<0xB1>(v);  /* quad xor 1 */ \
    v = qxor_add<0x4E>(v);  /* quad xor 2 */ \
} while (0)

__global__ __launch_bounds__(128) void wesper_kernel(
    const float* __restrict__ x,
    const float* __restrict__ d,
    const float* __restrict__ wd,
    const float* __restrict__ tau,
    const float* __restrict__ wt,
    float* __restrict__ out)
{
#pragma clang fp contract(off)
    const int tid = threadIdx.x;
    const int L   = tid & (GROUP - 1);
    const int gid = blockIdx.x * (blockDim.x / GROUP) + (tid >> 2);

    // numpy pairwise_sum_CFLOAT, n=128 complex: 4 accumulators, acc L sums
    // elements L, L+4, ..., L+124 sequentially.
    float tauC[CPN], wttC[CPN], cdC[CPN], wddC[CPN];
    #pragma unroll
    for (int t = 0; t < CPN; ++t) {
        int k = L + (t << 2);
        float tk = tau[k], wk = wt[k];
        tauC[t] = tk;
        wttC[t] = wk * tk;      // wt_tau (one f32 round)
        float dj = d[k];
        cdC[t]  = 0.5f * dj;    // c*d (exact halving)
        wddC[t] = wd[k] * dj;   // wd_d (one f32 round)
    }
    const float xv = x[gid];

    // m0 = np.sum(wd*d): real pairwise, 8 accumulators stride 8,
    // combine ((r0+r1)+(r2+r3)) + ((r4+r5)+(r6+r7)).
    float rAc = 0.0f, rBc = 0.0f;
    #pragma unroll
    for (int t = 0; t < 16; ++t) {
        int kA = L + (t << 3);
        int kB = kA + 4;
        float vA = wd[kA] * d[kA];
        float vB = wd[kB] * d[kB];
        rAc = (t == 0) ? vA : (rAc + vA);
        rBc = (t == 0) ? vB : (rBc + vB);
    }
    RED4(rAc);
    RED4(rBc);
    float m0 = rAc + rBc;

    float mr = m0, mi = -1.0f;

    for (int it = 0; it < NITER; ++it) {
        // ---- S = sum_k wt_tau_k / (tau_k*m - x), Smith div, STAGED 8-wide ----
        float sre = 0.0f, sim = 0.0f;
        #pragma unroll
        for (int g = 0; g < CPN / GS; ++g) {
            float u[GS], v[GS], r0[GS];
            bool  sw[GS];
            // stage 1: denominators + first rcp (8 in flight)
            #pragma unroll
            for (int j = 0; j < GS; ++j) {
                int t = g * GS + j;
                float dr = tauC[t] * mr - xv;   // mul, sub (no fma)
                float di = tauC[t] * mi;
                sw[j] = fabsf(di) > fabsf(dr);
                u[j]  = sw[j] ? di : dr;
                v[j]  = sw[j] ? dr : di;
                r0[j] = __builtin_amdgcn_rcpf(u[j]);
            }
            // stage 2: rat = v/u (Markstein, correctly rounded), den, second rcp
            float rat[GS], den[GS], r1[GS];
            #pragma unroll
            for (int j = 0; j < GS; ++j) {
                float r = r0[j];
                float e = __builtin_fmaf(-u[j], r, 1.0f);
                r = __builtin_fmaf(e, r, r);
                e = __builtin_fmaf(-u[j], r, 1.0f);
                r = __builtin_fmaf(e, r, r);
                float q = v[j] * r;
                float res = __builtin_fmaf(-u[j], q, v[j]);
                rat[j] = __builtin_fmaf(res, r, q);
                float w = v[j] * rat[j];
                den[j] = u[j] + w;
                r1[j] = __builtin_amdgcn_rcpf(den[j]);
            }
            // stage 3: scl = 1/den (Markstein; q=1*r==r), products, accumulate in t-order
            #pragma unroll
            for (int j = 0; j < GS; ++j) {
                int t = g * GS + j;
                float r = r1[j];
                float e = __builtin_fmaf(-den[j], r, 1.0f);
                r = __builtin_fmaf(e, r, r);
                e = __builtin_fmaf(-den[j], r, 1.0f);
                r = __builtin_fmaf(e, r, r);
                float res = __builtin_fmaf(-den[j], r, 1.0f);
                float scl = __builtin_fmaf(res, r, r);
                float nr  = wttC[t];
                float t1  = nr * rat[j];
                float qrn = sw[j] ? t1 : nr;    // A(|dr|>=|di|): nr   B: nr*rat
                float qin = sw[j] ? nr : t1;    // A: nr*rat           B: nr
                float qr  = qrn * scl;
                float qi  = -qin * scl;
                sre = (t == 0) ? qr : (sre + qr);
                sim = (t == 0) ? qi : (sim + qi);
            }
        }
        RED4(sre);
        RED4(sim);

        // ---- F = sum_j wd_d_j / (1 + (c*d_j)*S), same staged structure ----
        float fre = 0.0f, fim = 0.0f;
        #pragma unroll
        for (int g = 0; g < CPN / GS; ++g) {
            float u[GS], v[GS], r0[GS];
            bool  sw[GS];
            #pragma unroll
            for (int j = 0; j < GS; ++j) {
                int t = g * GS + j;
                float er = 1.0f + cdC[t] * sre;  // mul, add (no fma)
                float ei = cdC[t] * sim;
                sw[j] = fabsf(ei) > fabsf(er);
                u[j]  = sw[j] ? ei : er;
                v[j]  = sw[j] ? er : ei;
                r0[j] = __builtin_amdgcn_rcpf(u[j]);
            }
            float rat[GS], den[GS], r1[GS];
            #pragma unroll
            for (int j = 0; j < GS; ++j) {
                float r = r0[j];
                float e = __builtin_fmaf(-u[j], r, 1.0f);
                r = __builtin_fmaf(e, r, r);
                e = __builtin_fmaf(-u[j], r, 1.0f);
                r = __builtin_fmaf(e, r, r);
                float q = v[j] * r;
                float res = __builtin_fmaf(-u[j], q, v[j]);
                rat[j] = __builtin_fmaf(res, r, q);
                float w = v[j] * rat[j];
                den[j] = u[j] + w;
                r1[j] = __builtin_amdgcn_rcpf(den[j]);
            }
            #pragma unroll
            for (int j = 0; j < GS; ++j) {
                int t = g * GS + j;
                float r = r1[j];
                float e = __builtin_fmaf(-den[j], r, 1.0f);
                r = __builtin_fmaf(e, r, r);
                e = __builtin_fmaf(-den[j], r, 1.0f);
                r = __builtin_fmaf(e, r, r);
                float res = __builtin_fmaf(-den[j], r, 1.0f);
                float scl = __builtin_fmaf(res, r, r);
                float nr  = wddC[t];
                float t1  = nr * rat[j];
                float qrn = sw[j] ? t1 : nr;
                float qin = sw[j] ? nr : t1;
                float qr  = qrn * scl;
                float qi  = -qin * scl;
                fre = (t == 0) ? qr : (fre + qr);
                fim = (t == 0) ? qi : (fim + qi);
            }
        }
        RED4(fre);
        RED4(fim);

        float mnre = fre;
        float mnim = fminf(fim, -1e-10f);   // Im < 0 branch clamp
        mr = 0.5f * mr + 0.5f * mnre;       // exact halvings + one add round
        mi = 0.5f * mi + 0.5f * mnim;
    }

    // ---- m(x) = sum_k wt_k / (tau_k*m_tilde - x), staged the same way ----
    float ore = 0.0f, oim = 0.0f;
    #pragma unroll
    for (int g = 0; g < CPN / GS; ++g) {
        float u[GS], v[GS], r0[GS];
        bool  sw[GS];
        #pragma unroll
        for (int j = 0; j < GS; ++j) {
            int t = g * GS + j;
            float dr = tauC[t] * mr - xv;
            float di = tauC[t] * mi;
            sw[j] = fabsf(di) > fabsf(dr);
            u[j]  = sw[j] ? di : dr;
            v[j]  = sw[j] ? dr : di;
            r0[j] = __builtin_amdgcn_rcpf(u[j]);
        }
        float rat[GS], den[GS], r1[GS];
        #pragma unroll
        for (int j = 0; j < GS; ++j) {
            float r = r0[j];
            float e = __builtin_fmaf(-u[j], r, 1.0f);
            r = __builtin_fmaf(e, r, r);
            e = __builtin_fmaf(-u[j], r, 1.0f);
            r = __builtin_fmaf(e, r, r);
            float q = v[j] * r;
            float res = __builtin_fmaf(-u[j], q, v[j]);
            rat[j] = __builtin_fmaf(res, r, q);
            float w = v[j] * rat[j];
            den[j] = u[j] + w;
            r1[j] = __builtin_amdgcn_rcpf(den[j]);
        }
        #pragma unroll
        for (int j = 0; j < GS; ++j) {
            int t = g * GS + j;
            int k = L + (t << 2);
            float r = r1[j];
            float e = __builtin_fmaf(-den[j], r, 1.0f);
            r = __builtin_fmaf(e, r, r);
            e = __builtin_fmaf(-den[j], r, 1.0f);
            r = __builtin_fmaf(e, r, r);
            float res = __builtin_fmaf(-den[j], r, 1.0f);
            float scl = __builtin_fmaf(res, r, r);
            float nr  = wt[k];
            float t1  = nr * rat[j];
            float qrn = sw[j] ? t1 : nr;
            float qin = sw[j] ? nr : t1;
            float qr  = qrn * scl;
            float qi  = -qin * scl;
            ore = (t == 0) ? qr : (ore + qr);
            oim = (t == 0) ? qi : (oim + qi);
        }
    }
    RED4(ore);
    RED4(oim);

    if (L == 0) {
        // Layout (verified passing R7-R14): [f | m.real | X.real], 24576 floats.
        out[gid]           = (float)((double)fabsf(oim) / 3.141592653589793);
        out[NXP + gid]     = ore;
        // X.real = (0 - mr) * (1/x), numpy Smith with zero-imag denominator.
        float r = __builtin_amdgcn_rcpf(xv);
        float e = __builtin_fmaf(-xv, r, 1.0f);
        r = __builtin_fmaf(e, r, r);
        e = __builtin_fmaf(-xv, r, 1.0f);
        r = __builtin_fmaf(e, r, r);
        float res = __builtin_fmaf(-xv, r, 1.0f);
        float scl = __builtin_fmaf(res, r, r);
        out[2 * NXP + gid] = -mr * scl;
    }
}

extern "C" void kernel_launch(void* const* d_in, const int* in_sizes, int n_in,
                              void* d_out, int out_size, void* d_ws, size_t ws_size,
                              hipStream_t stream) {
    const float* x   = (const float*)d_in[0];
    const float* d   = (const float*)d_in[1];
    const float* wd  = (const float*)d_in[2];
    const float* tau = (const float*)d_in[3];
    const float* wt  = (const float*)d_in[4];
    float* out = (float*)d_out;

    // 128 threads/block = 32 points/block -> 256 blocks (1 per CU, 2 waves each).
    const int pts_per_block = 128 / GROUP;
    const int nblocks = NXP / pts_per_block;
    wesper_kernel<<<nblocks, 128, 0, stream>>>(x, d, wd, tau, wt, out);
}